// Round 7
// baseline (153.468 us; speedup 1.0000x reference)
//
#include <hip/hip_runtime.h>

#define BATCH 32
#define NOBJ  64
#define PADK  264   // halfs; A-tile row stride 528 B (16B-aligned)

typedef _Float16 f16x2 __attribute__((ext_vector_type(2)));
typedef __fp16   h16x2 __attribute__((ext_vector_type(2)));
typedef _Float16 f16x4 __attribute__((ext_vector_type(4)));
typedef _Float16 f16x8 __attribute__((ext_vector_type(8)));
typedef float    f32x4 __attribute__((ext_vector_type(4)));
typedef float    f32x16 __attribute__((ext_vector_type(16)));

#define MFMA32(a, b, c) __builtin_amdgcn_mfma_f32_32x32x16_f16((a), (b), (c), 0, 0, 0)

// ---------------------------------------------------------------------------
// Layer-0 removed from the MFMA loop (exact algebra):
//   h1[b][(i,j)][n] = relu( h0j[b][j][n] + cib[b][i][n] )
//
// R7: R6 cycle audit -- true matrix-pipe busy ~10%, per-wave issue cost
// ~1.4K cyc vs ~18K wall (13x slack): the kk loop is LATENCY-SERIAL.
// Cause: VGPR_Count=128 + 128 AGPR acc = 256/thread = the 2-waves/SIMD
// cap; the allocator has no headroom to hoist loads, so every kk eats
// its own ~200cy B + ~120cy A latency (16 x ~1.1K = measured per-layer
// wall). Fix: keep R6's geometry (Mt4xNt2, B-once, 4 waves, identity
// layouts -- all measured best) and buy scheduling headroom:
//  * __launch_bounds__(256, 1): lift the 128-arch-VGPR cap.
//  * depth-4 B-ring (both streams) + depth-2 A-ring, fully unrolled,
//    static indices; layer l's kk>=12 issues layer l+1's first 4 B-pairs
//    (hot restart across the epilogue barriers).
// Confirmation signal: VGPR_Count ~180-256 (if it stays 128 the probe is
// void). Bet: ILP-pipelining > lost TLP (R6 shows TLP wasn't hiding it).
// ---------------------------------------------------------------------------

// ---------------------------------------------------------------------------
// Kernel 0: prep_all.  (unchanged)
// blk 0..31  : zero xg; repack weights l=blk>>3 in MFMA B-fragment order
//              (skip l==0 -- unused):
//              wtf[l][ngrp=8][kk=16][lane=64][j=8] = W_l[k][nlog]
//              nlog = ngrp*32+(lane&31), k = kk*16+(lane>>5)*8+j
// blk 32..543: cib (per-(b, 4 i's)); thread t = col n.
// blk 544..799: h0j (per-(b, 8 j's)); thread t = col n.
// ---------------------------------------------------------------------------
__global__ __launch_bounds__(256) void prep_all(
    const float* __restrict__ x_aux,
    const float* __restrict__ g1w, const float* __restrict__ g1b,
    const float* __restrict__ g2w, const float* __restrict__ g3w,
    const float* __restrict__ g4w,
    _Float16* __restrict__ wtf, float* __restrict__ xg,
    float* __restrict__ cib, float* __restrict__ h0j) {
  __shared__ __align__(16) _Float16 tile[256][33];
  const int blk = blockIdx.x;
  const int t = threadIdx.x;

  if (blk < 32) {
    xg[blk * 256 + t] = 0.0f;
    const int l = blk >> 3;
    if (l == 0) return;                 // layer-0 weights not needed
    const int nt = blk & 7;
    const float* src = (l == 1) ? g2w : (l == 2) ? g3w : g4w;

    const int nn = t & 31, kb = t >> 5;
#pragma unroll 4
    for (int pass = 0; pass < 32; ++pass) {
      int kp = pass * 8 + kb;
      tile[kp][nn] = (_Float16)src[(size_t)kp * 256 + nt * 32 + nn];
    }
    __syncthreads();

    const int lane = t & 63;
    const int nfrag = lane & 31;
    const int kbase = (lane >> 5) * 8;
    _Float16* dst = wtf + ((size_t)(l * 8 + nt) * 16) * 512;
#pragma unroll
    for (int q = 0; q < 4; ++q) {
      int kk = (t >> 6) + 4 * q;
      f16x8 fr;
#pragma unroll
      for (int j = 0; j < 8; ++j)
        fr[j] = tile[kk * 16 + kbase + j][nfrag];
      *(f16x8*)(dst + (size_t)kk * 512 + lane * 8) = fr;
    }
  } else if (blk < 544) {
    // ---- cib = x_i . W0[65:193] + i*W0[193] + b1  (fp32) ----
    float* xs = (float*)&tile[0][0];     // [4][128]
    const int blkc = blk - 32;           // 512 = 32 b x 16 groups
    const int b  = blkc >> 4;
    const int i0 = (blkc & 15) * 4;

#pragma unroll
    for (int u = 0; u < 2; ++u) {
      int idx = u * 256 + t;
      int j = idx >> 7, k = idx & 127;
      xs[j * 128 + k] = x_aux[((size_t)(b * NOBJ + i0 + j)) * 128 + k];
    }
    __syncthreads();

    float c0 = 0.f, c1 = 0.f, c2 = 0.f, c3 = 0.f;
#pragma unroll 2
    for (int k = 0; k < 128; k += 4) {
      f32x4 x0 = *(const f32x4*)&xs[k];
      f32x4 x1 = *(const f32x4*)&xs[128 + k];
      f32x4 x2 = *(const f32x4*)&xs[256 + k];
      f32x4 x3 = *(const f32x4*)&xs[384 + k];
#pragma unroll
      for (int q = 0; q < 4; ++q) {
        float w = g1w[(size_t)(65 + k + q) * 256 + t];
        c0 += x0[q] * w; c1 += x1[q] * w;
        c2 += x2[q] * w; c3 += x3[q] * w;
      }
    }
    float wc = g1w[(size_t)193 * 256 + t];
    float bb = g1b[t];
    c0 += (float)(i0 + 0) * wc + bb;
    c1 += (float)(i0 + 1) * wc + bb;
    c2 += (float)(i0 + 2) * wc + bb;
    c3 += (float)(i0 + 3) * wc + bb;
    cib[((size_t)(b * NOBJ + i0 + 0)) * 256 + t] = c0;
    cib[((size_t)(b * NOBJ + i0 + 1)) * 256 + t] = c1;
    cib[((size_t)(b * NOBJ + i0 + 2)) * 256 + t] = c2;
    cib[((size_t)(b * NOBJ + i0 + 3)) * 256 + t] = c3;
  } else {
    // ---- h0j = x_j . W0[0:64] + j*W0[64]  (fp32, no bias) ----
    float* xs = (float*)&tile[0][0];     // [8][68]
    const int blk2 = blk - 544;          // 256 = 32 b x 8 jgroups
    const int b  = blk2 >> 3;
    const int j0 = (blk2 & 7) * 8;

#pragma unroll
    for (int u = 0; u < 2; ++u) {
      int idx = u * 256 + t;             // 0..511
      int jj = idx >> 6, k = idx & 63;
      xs[jj * 68 + k] = x_aux[((size_t)(b * NOBJ + j0 + jj)) * 128 + k];
    }
    __syncthreads();

    float acc[8] = {};
#pragma unroll 2
    for (int k = 0; k < 64; k += 4) {
      f32x4 xv[8];
#pragma unroll
      for (int jj = 0; jj < 8; ++jj)
        xv[jj] = *(const f32x4*)&xs[jj * 68 + k];
#pragma unroll
      for (int q = 0; q < 4; ++q) {
        float w = g1w[(size_t)(k + q) * 256 + t];
#pragma unroll
        for (int jj = 0; jj < 8; ++jj) acc[jj] += xv[jj][q] * w;
      }
    }
    float wc = g1w[(size_t)64 * 256 + t];   // coord column
#pragma unroll
    for (int jj = 0; jj < 8; ++jj)
      h0j[((size_t)(b * NOBJ + j0 + jj)) * 256 + t] =
          acc[jj] + (float)(j0 + jj) * wc;
  }
}

// ---------------------------------------------------------------------------
// One layer's 16 k-steps: Mt=4 x Nt=2, pipelined.
// Entry state: av[0]=A(0), av[1]=A(1) (4 m-frags each), u0/u1 = B(0..3).
// Step kk: 8 MFMAs from av[kk&1], u*[kk&3]; then issue A(kk+2) into
// av[kk&1] and B(kk+4) into u*[kk&3] (kk>=12: NEXT layer's B(kk-12)).
// Exit state: u0/u1 hold next layer's B(0..3). All indices static.
// ---------------------------------------------------------------------------
template <bool PRELOAD_NEXT>
__device__ __forceinline__ void layer_run(
    const _Float16* __restrict__ bp0, const _Float16* __restrict__ bp1,
    const _Float16* __restrict__ bn0, const _Float16* __restrict__ bn1,
    const _Float16* __restrict__ arow,
    f16x8 (&av)[2][4], f16x8 (&u0)[4], f16x8 (&u1)[4],
    f32x16 (&acc)[8]) {
  // preload A(0), A(1)
#pragma unroll
  for (int p = 0; p < 2; ++p)
#pragma unroll
    for (int m = 0; m < 4; ++m)
      av[p][m] = *(const f16x8*)(arow + (size_t)m * 32 * PADK + p * 16);

#pragma unroll
  for (int kk = 0; kk < 16; ++kk) {
    f16x8 b0 = u0[kk & 3];
    f16x8 b1 = u1[kk & 3];
#pragma unroll
    for (int m = 0; m < 4; ++m) {
      f16x8 a = av[kk & 1][m];
      acc[m * 2]     = MFMA32(a, b0, acc[m * 2]);
      acc[m * 2 + 1] = MFMA32(a, b1, acc[m * 2 + 1]);
    }
    if (kk < 14) {
#pragma unroll
      for (int m = 0; m < 4; ++m)
        av[kk & 1][m] =
            *(const f16x8*)(arow + (size_t)m * 32 * PADK + (kk + 2) * 16);
    }
    if (kk < 12) {
      u0[kk & 3] = *(const f16x8*)(bp0 + (size_t)(kk + 4) * 512);
      u1[kk & 3] = *(const f16x8*)(bp1 + (size_t)(kk + 4) * 512);
    } else if constexpr (PRELOAD_NEXT) {
      u0[kk & 3] = *(const f16x8*)(bn0 + (size_t)(kk - 12) * 512);
      u1[kk & 3] = *(const f16x8*)(bn1 + (size_t)(kk - 12) * 512);
    }
  }
}

// ---------------------------------------------------------------------------
// Kernel 1: fused g-MLP layers 1-3 + sum-pool for TWO i's per block.
// Block = 256 thr (4 waves). M=128 (2 i's x 64 j), N=256, K=256.
// Wave wv owns n-groups 2wv,2wv+1 (n0=wv*64), Mt=4 (ALL 128 rows):
// 4 A-reads feed 8 MFMAs per kk; B read once per block per layer.
// __launch_bounds__(256,1): allow >128 arch VGPR so the rings stay
// in registers (R6's 128-cap made every kk latency-serial).
// ---------------------------------------------------------------------------
__global__ __launch_bounds__(256, 1) void g_mlp_pool(
    const float* __restrict__ h0j,            // [B*64][256] fp32
    const float* __restrict__ cib,            // [B*64][256] fp32
    const _Float16* __restrict__ wtf,         // fragment-ordered
    const float* __restrict__ g2b, const float* __restrict__ g3b,
    const float* __restrict__ g4b,
    float* __restrict__ xg) {                 // [B][256] fp32 (pre-zeroed)
  __shared__ __align__(16) _Float16 As[128][PADK];  // 67.6 KB

  const int b  = blockIdx.x >> 5;
  const int i0 = (blockIdx.x & 31) * 2;
  const int t  = threadIdx.x;
  const int lane = t & 63;
  const int wv   = t >> 6;                    // 0..3 = this wave's N-pair

  const int c31  = lane & 31;
  const int h    = lane >> 5;       // 0/1 (k-half of fragments)
  const int n0   = wv * 64;

  // identity k-order weight bases: layer l, n-group g:
  // wtf + ((l*8+g)*16 + kk)*512 + lane*8 ; stream1 = stream0 + 16*512.
  const _Float16* L1 = wtf + ((size_t)(8  + 2 * wv) * 16) * 512 + lane * 8;
  const _Float16* L2 = wtf + ((size_t)(16 + 2 * wv) * 16) * 512 + lane * 8;
  const _Float16* L3 = wtf + ((size_t)(24 + 2 * wv) * 16) * 512 + lane * 8;

  // B-ring preload: layer-1 kk=0..3 (independent of As build)
  f16x8 u0[4], u1[4];
#pragma unroll
  for (int q = 0; q < 4; ++q) {
    u0[q] = *(const f16x8*)(L1 + (size_t)q * 512);
    u1[q] = *(const f16x8*)(L1 + 16 * 512 + (size_t)q * 512);
  }

  // ---- build act1 tile: rows j and 64+j share the same h0j row ----
  {
    const int c = lane * 4;                   // this lane's 4 cols
    const float* hb = h0j + (size_t)(b * NOBJ) * 256 + c;
    const float* c0p = cib + (size_t)(b * NOBJ + i0) * 256 + c;
    f32x4 cv0 = *(const f32x4*)c0p;
    f32x4 cv1 = *(const f32x4*)(c0p + 256);
#pragma unroll
    for (int it = 0; it < 16; ++it) {
      int j = it * 4 + wv;
      f32x4 hv = *(const f32x4*)(hb + (size_t)j * 256);
      f16x4 p0, p1;
#pragma unroll
      for (int q = 0; q < 4; ++q) {
        p0[q] = (_Float16)fmaxf(hv[q] + cv0[q], 0.f);
        p1[q] = (_Float16)fmaxf(hv[q] + cv1[q], 0.f);
      }
      *(f16x4*)&As[j][c]      = p0;
      *(f16x4*)&As[64 + j][c] = p1;
    }
  }
  __syncthreads();

  const _Float16* arow = &As[c31][h * 8];
  const float bv20 = g2b[n0 + c31], bv21 = g2b[n0 + 32 + c31];
  const float bv30 = g3b[n0 + c31], bv31 = g3b[n0 + 32 + c31];
  const float bv40 = g4b[n0 + c31], bv41 = g4b[n0 + 32 + c31];

  f16x8 av[2][4];
  f32x16 acc[8];   // [m*2 + ns]

  // ================= layer 1 =================
#pragma unroll
  for (int x = 0; x < 8; ++x) acc[x] = (f32x16){};
  layer_run<true>(L1, L1 + 16 * 512, L2, L2 + 16 * 512, arow, av, u0, u1, acc);

  __syncthreads();   // all waves done reading As
  // C/D layout: col = lane&31, row = (reg&3) + 8*(reg>>2) + 4*h.
  // Identity act layout: contiguous 64B runs -> conflict-free.
#pragma unroll
  for (int m = 0; m < 4; ++m)
#pragma unroll
    for (int g = 0; g < 4; ++g)
#pragma unroll
      for (int r = 0; r < 4; ++r) {
        const int row = m * 32 + g * 8 + h * 4 + r;
        const int reg = g * 4 + r;
        As[row][n0 + c31]      = (_Float16)fmaxf(acc[m * 2][reg] + bv20, 0.f);
        As[row][n0 + 32 + c31] = (_Float16)fmaxf(acc[m * 2 + 1][reg] + bv21, 0.f);
      }
  __syncthreads();

  // ================= layer 2 =================
#pragma unroll
  for (int x = 0; x < 8; ++x) acc[x] = (f32x16){};
  layer_run<true>(L2, L2 + 16 * 512, L3, L3 + 16 * 512, arow, av, u0, u1, acc);

  __syncthreads();
#pragma unroll
  for (int m = 0; m < 4; ++m)
#pragma unroll
    for (int g = 0; g < 4; ++g)
#pragma unroll
      for (int r = 0; r < 4; ++r) {
        const int row = m * 32 + g * 8 + h * 4 + r;
        const int reg = g * 4 + r;
        As[row][n0 + c31]      = (_Float16)fmaxf(acc[m * 2][reg] + bv30, 0.f);
        As[row][n0 + 32 + c31] = (_Float16)fmaxf(acc[m * 2 + 1][reg] + bv31, 0.f);
      }
  __syncthreads();

  // ================= layer 3 + pool =================
#pragma unroll
  for (int x = 0; x < 8; ++x) acc[x] = (f32x16){};
  layer_run<false>(L3, L3 + 16 * 512, nullptr, nullptr, arow, av, u0, u1, acc);

  // bias + relu + pool over all 128 rows (this lane's h-half of every
  // m-tile = 64 rows); shfl_xor(32) folds the h-halves.
  float s0 = 0.f, s1 = 0.f;
#pragma unroll
  for (int m = 0; m < 4; ++m)
#pragma unroll
    for (int reg = 0; reg < 16; ++reg) {
      s0 += fmaxf(acc[m * 2][reg] + bv40, 0.f);
      s1 += fmaxf(acc[m * 2 + 1][reg] + bv41, 0.f);
    }
  s0 += __shfl_xor(s0, 32, 64);
  s1 += __shfl_xor(s1, 32, 64);
  if (h == 0) {
    atomicAdd(&xg[b * 256 + n0 + c31], s0);
    atomicAdd(&xg[b * 256 + n0 + 32 + c31], s1);
  }
}

// ---------------------------------------------------------------------------
// Kernel 2: f-MLP. One block per batch, 1024 threads: n = t&255 owns column,
// kc = t>>8 owns a 64-wide k-chunk; LDS reduce the 4 partials per column.
// ---------------------------------------------------------------------------
__global__ __launch_bounds__(1024) void f_mlp(
    const float* __restrict__ xg,
    const float* __restrict__ f1w, const float* __restrict__ f1b,
    const float* __restrict__ f2w, const float* __restrict__ f2b,
    const float* __restrict__ f3w, const float* __restrict__ f3b,
    float* __restrict__ out) {
  __shared__ float xs[256], ys[256], ps[4][256];
  const int b = blockIdx.x;
  const int t = threadIdx.x;
  const int n = t & 255;
  const int kc = t >> 8;

  if (t < 256) xs[t] = xg[b * 256 + t];
  __syncthreads();

  float p = 0.f;
#pragma unroll 8
  for (int k0 = 0; k0 < 64; ++k0) {
    int k = kc * 64 + k0;
    p += xs[k] * f1w[k * 256 + n];
  }
  ps[kc][n] = p;
  __syncthreads();
  if (t < 256)
    ys[t] = fmaxf(f1b[t] + ps[0][t] + ps[1][t] + ps[2][t] + ps[3][t], 0.f);
  __syncthreads();

  p = 0.f;
#pragma unroll 8
  for (int k0 = 0; k0 < 64; ++k0) {
    int k = kc * 64 + k0;
    p += ys[k] * f2w[k * 256 + n];
  }
  ps[kc][n] = p;
  __syncthreads();
  if (t < 256)
    xs[t] = fmaxf(f2b[t] + ps[0][t] + ps[1][t] + ps[2][t] + ps[3][t], 0.f);
  __syncthreads();

  p = 0.f;
#pragma unroll 8
  for (int k0 = 0; k0 < 64; ++k0) {
    int k = kc * 64 + k0;
    p += xs[k] * f3w[k * 256 + n];
  }
  ps[kc][n] = p;
  __syncthreads();
  if (t < 256)
    out[b * 256 + t] = f3b[t] + ps[0][t] + ps[1][t] + ps[2][t] + ps[3][t];
}

// ---------------------------------------------------------------------------
extern "C" void kernel_launch(void* const* d_in, const int* in_sizes, int n_in,
                              void* d_out, int out_size, void* d_ws, size_t ws_size,
                              hipStream_t stream) {
  const float* x_aux = (const float*)d_in[0];
  const float* g1w = (const float*)d_in[1];
  const float* g1b = (const float*)d_in[2];
  const float* g2w = (const float*)d_in[3];
  const float* g2b = (const float*)d_in[4];
  const float* g3w = (const float*)d_in[5];
  const float* g3b = (const float*)d_in[6];
  const float* g4w = (const float*)d_in[7];
  const float* g4b = (const float*)d_in[8];
  const float* f1w = (const float*)d_in[9];
  const float* f1b = (const float*)d_in[10];
  const float* f2w = (const float*)d_in[11];
  const float* f2b = (const float*)d_in[12];
  const float* f3w = (const float*)d_in[13];
  const float* f3b = (const float*)d_in[14];
  float* out = (float*)d_out;

  _Float16* wtf = (_Float16*)d_ws;                                  // 512 KB
  float* xg  = (float*)((char*)d_ws + 512u * 1024u);                // 32 KB
  float* cib = (float*)((char*)d_ws + 544u * 1024u);                // 2 MB
  float* h0j = (float*)((char*)d_ws + 544u * 1024u + 2048u * 1024u);// 2 MB

  hipLaunchKernelGGL(prep_all, dim3(800), dim3(256), 0, stream,
                     x_aux, g1w, g1b, g2w, g3w, g4w, wtf, xg, cib, h0j);
  hipLaunchKernelGGL(g_mlp_pool, dim3(BATCH * 32), dim3(256), 0, stream,
                     h0j, cib, wtf, g2b, g3b, g4b, xg);
  hipLaunchKernelGGL(f_mlp, dim3(BATCH), dim3(1024), 0, stream,
                     xg, f1w, f1b, f2w, f2b, f3w, f3b, out);
}

// Round 8
// 147.213 us; speedup vs baseline: 1.0425x; 1.0425x over previous
//
#include <hip/hip_runtime.h>

#define BATCH 32
#define NOBJ  64
#define PADK  264   // halfs; A-tile row stride 528 B (16B-aligned)

typedef _Float16 f16x2 __attribute__((ext_vector_type(2)));
typedef __fp16   h16x2 __attribute__((ext_vector_type(2)));
typedef _Float16 f16x4 __attribute__((ext_vector_type(4)));
typedef _Float16 f16x8 __attribute__((ext_vector_type(8)));
typedef float    f32x4 __attribute__((ext_vector_type(4)));
typedef float    f32x16 __attribute__((ext_vector_type(16)));

#define MFMA32(a, b, c) __builtin_amdgcn_mfma_f32_32x32x16_f16((a), (b), (c), 0, 0, 0)

// ---------------------------------------------------------------------------
// Layer-0 removed from the MFMA loop (exact algebra):
//   h1[b][(i,j)][n] = relu( h0j[b][j][n] + cib[b][i][n] )
//
// R8 = R6 (best measured: g_mlp 52.5us) + bijective XCD swizzle.
// Session ledger: R1-R7 swept occupancy (2-4 w/SIMD), B-traffic (1-2x),
// prefetch rings (depth 0/2/4/8, VGPR-capped and uncapped), barrier count
// (7 vs 3), launch bounds -- g_mlp spans 52.5-64us, compiler-scheduled
// R6 (Mt4xNt2, 4 waves, plain in-loop loads) is the floor of the family.
// Manual pipelining is 0-for-3 (compiler re-schedules; m97-ceiling
// precedent). Remaining dur_us is ~60% harness floor (20 dispatches/iter,
// 17 non-kernel) -- totals are uncorrelated with g_mlp across 8 rounds.
//
// XCD swizzle (T1): blocks sharing b are consecutive; default round-robin
// scatters them over 8 XCDs so every XCD refetches all h0j/cib
// (FETCH 10.9MB ~ 2.4x unique). wgid=(bid&7)*128+bid/8 (1024%8==0 ->
// bijective) gives each XCD 4 contiguous b's (~1MB < 4MB L2): build +
// B-restart loads become L2 hits in a latency-dominated kernel.
// Mechanism check: FETCH_SIZE should drop to ~5-6.5MB.
// ---------------------------------------------------------------------------

// ---------------------------------------------------------------------------
// Kernel 0: prep_all.  (unchanged)
// blk 0..31  : zero xg; repack weights l=blk>>3 in MFMA B-fragment order
//              (skip l==0 -- unused):
//              wtf[l][ngrp=8][kk=16][lane=64][j=8] = W_l[k][nlog]
//              nlog = ngrp*32+(lane&31), k = kk*16+(lane>>5)*8+j
// blk 32..543: cib (per-(b, 4 i's)); thread t = col n.
// blk 544..799: h0j (per-(b, 8 j's)); thread t = col n.
// ---------------------------------------------------------------------------
__global__ __launch_bounds__(256) void prep_all(
    const float* __restrict__ x_aux,
    const float* __restrict__ g1w, const float* __restrict__ g1b,
    const float* __restrict__ g2w, const float* __restrict__ g3w,
    const float* __restrict__ g4w,
    _Float16* __restrict__ wtf, float* __restrict__ xg,
    float* __restrict__ cib, float* __restrict__ h0j) {
  __shared__ __align__(16) _Float16 tile[256][33];
  const int blk = blockIdx.x;
  const int t = threadIdx.x;

  if (blk < 32) {
    xg[blk * 256 + t] = 0.0f;
    const int l = blk >> 3;
    if (l == 0) return;                 // layer-0 weights not needed
    const int nt = blk & 7;
    const float* src = (l == 1) ? g2w : (l == 2) ? g3w : g4w;

    const int nn = t & 31, kb = t >> 5;
#pragma unroll 4
    for (int pass = 0; pass < 32; ++pass) {
      int kp = pass * 8 + kb;
      tile[kp][nn] = (_Float16)src[(size_t)kp * 256 + nt * 32 + nn];
    }
    __syncthreads();

    const int lane = t & 63;
    const int nfrag = lane & 31;
    const int kbase = (lane >> 5) * 8;
    _Float16* dst = wtf + ((size_t)(l * 8 + nt) * 16) * 512;
#pragma unroll
    for (int q = 0; q < 4; ++q) {
      int kk = (t >> 6) + 4 * q;
      f16x8 fr;
#pragma unroll
      for (int j = 0; j < 8; ++j)
        fr[j] = tile[kk * 16 + kbase + j][nfrag];
      *(f16x8*)(dst + (size_t)kk * 512 + lane * 8) = fr;
    }
  } else if (blk < 544) {
    // ---- cib = x_i . W0[65:193] + i*W0[193] + b1  (fp32) ----
    float* xs = (float*)&tile[0][0];     // [4][128]
    const int blkc = blk - 32;           // 512 = 32 b x 16 groups
    const int b  = blkc >> 4;
    const int i0 = (blkc & 15) * 4;

#pragma unroll
    for (int u = 0; u < 2; ++u) {
      int idx = u * 256 + t;
      int j = idx >> 7, k = idx & 127;
      xs[j * 128 + k] = x_aux[((size_t)(b * NOBJ + i0 + j)) * 128 + k];
    }
    __syncthreads();

    float c0 = 0.f, c1 = 0.f, c2 = 0.f, c3 = 0.f;
#pragma unroll 2
    for (int k = 0; k < 128; k += 4) {
      f32x4 x0 = *(const f32x4*)&xs[k];
      f32x4 x1 = *(const f32x4*)&xs[128 + k];
      f32x4 x2 = *(const f32x4*)&xs[256 + k];
      f32x4 x3 = *(const f32x4*)&xs[384 + k];
#pragma unroll
      for (int q = 0; q < 4; ++q) {
        float w = g1w[(size_t)(65 + k + q) * 256 + t];
        c0 += x0[q] * w; c1 += x1[q] * w;
        c2 += x2[q] * w; c3 += x3[q] * w;
      }
    }
    float wc = g1w[(size_t)193 * 256 + t];
    float bb = g1b[t];
    c0 += (float)(i0 + 0) * wc + bb;
    c1 += (float)(i0 + 1) * wc + bb;
    c2 += (float)(i0 + 2) * wc + bb;
    c3 += (float)(i0 + 3) * wc + bb;
    cib[((size_t)(b * NOBJ + i0 + 0)) * 256 + t] = c0;
    cib[((size_t)(b * NOBJ + i0 + 1)) * 256 + t] = c1;
    cib[((size_t)(b * NOBJ + i0 + 2)) * 256 + t] = c2;
    cib[((size_t)(b * NOBJ + i0 + 3)) * 256 + t] = c3;
  } else {
    // ---- h0j = x_j . W0[0:64] + j*W0[64]  (fp32, no bias) ----
    float* xs = (float*)&tile[0][0];     // [8][68]
    const int blk2 = blk - 544;          // 256 = 32 b x 8 jgroups
    const int b  = blk2 >> 3;
    const int j0 = (blk2 & 7) * 8;

#pragma unroll
    for (int u = 0; u < 2; ++u) {
      int idx = u * 256 + t;             // 0..511
      int jj = idx >> 6, k = idx & 63;
      xs[jj * 68 + k] = x_aux[((size_t)(b * NOBJ + j0 + jj)) * 128 + k];
    }
    __syncthreads();

    float acc[8] = {};
#pragma unroll 2
    for (int k = 0; k < 64; k += 4) {
      f32x4 xv[8];
#pragma unroll
      for (int jj = 0; jj < 8; ++jj)
        xv[jj] = *(const f32x4*)&xs[jj * 68 + k];
#pragma unroll
      for (int q = 0; q < 4; ++q) {
        float w = g1w[(size_t)(k + q) * 256 + t];
#pragma unroll
        for (int jj = 0; jj < 8; ++jj) acc[jj] += xv[jj][q] * w;
      }
    }
    float wc = g1w[(size_t)64 * 256 + t];   // coord column
#pragma unroll
    for (int jj = 0; jj < 8; ++jj)
      h0j[((size_t)(b * NOBJ + j0 + jj)) * 256 + t] =
          acc[jj] + (float)(j0 + jj) * wc;
  }
}

// ---------------------------------------------------------------------------
// Kernel 1: fused g-MLP layers 1-3 + sum-pool for TWO i's per block.
// Block = 256 thr (4 waves). M=128 (2 i's x 64 j), N=256, K=256.
// Wave wv owns n-groups 2wv,2wv+1 (n0=wv*64), Mt=4 (ALL 128 rows):
// per kk, 4 A ds_reads feed 8 MFMAs (0.5 KB LDS per MFMA) AND B is read
// once per block per layer. acc = 8 x f32x16 = 128 AGPR ->
// __launch_bounds__(256,2), 2 blocks/CU. XCD-swizzled blockIdx: each
// XCD gets 4 contiguous batches -> h0j/cib/wtf L2-resident per XCD.
// ---------------------------------------------------------------------------
__global__ __launch_bounds__(256, 2) void g_mlp_pool(
    const float* __restrict__ h0j,            // [B*64][256] fp32
    const float* __restrict__ cib,            // [B*64][256] fp32
    const _Float16* __restrict__ wtf,         // fragment-ordered
    const float* __restrict__ g2b, const float* __restrict__ g3b,
    const float* __restrict__ g4b,
    float* __restrict__ xg) {                 // [B][256] fp32 (pre-zeroed)
  __shared__ __align__(16) _Float16 As[128][PADK];  // 67.6 KB -> 2 blocks/CU

  // bijective XCD swizzle: nwg=1024, nwg%8==0. XCD x hosts wgid in
  // [x*128,(x+1)*128) = batches [4x,4x+4): ~1MB footprint < 4MB L2.
  const int bid  = blockIdx.x;
  const int wgid = (bid & 7) * 128 + (bid >> 3);
  const int b  = wgid >> 5;
  const int i0 = (wgid & 31) * 2;
  const int t  = threadIdx.x;
  const int lane = t & 63;
  const int wv   = t >> 6;                    // 0..3 = this wave's N-pair

  // ---- build act1 tile: rows j and 64+j share the same h0j row ----
  {
    const int c = lane * 4;                   // this lane's 4 cols
    const float* hb = h0j + (size_t)(b * NOBJ) * 256 + c;
    const float* c0p = cib + (size_t)(b * NOBJ + i0) * 256 + c;
    f32x4 cv0 = *(const f32x4*)c0p;
    f32x4 cv1 = *(const f32x4*)(c0p + 256);
#pragma unroll
    for (int it = 0; it < 16; ++it) {
      int j = it * 4 + wv;
      f32x4 hv = *(const f32x4*)(hb + (size_t)j * 256);
      f16x4 p0, p1;
#pragma unroll
      for (int q = 0; q < 4; ++q) {
        p0[q] = (_Float16)fmaxf(hv[q] + cv0[q], 0.f);
        p1[q] = (_Float16)fmaxf(hv[q] + cv1[q], 0.f);
      }
      *(f16x4*)&As[j][c]      = p0;
      *(f16x4*)&As[64 + j][c] = p1;
    }
  }
  __syncthreads();

  const int c31  = lane & 31;
  const int h    = lane >> 5;       // 0/1 (k-half of fragments)
  const int n0   = wv * 64;
  const float* gb[4] = {nullptr, g2b, g3b, g4b};

  const _Float16* arow = &As[c31][h * 8];

  for (int layer = 1; layer < 4; ++layer) {
    const float bv0 = gb[layer][n0 + c31];
    const float bv1 = gb[layer][n0 + 32 + c31];

    f32x16 acc[8];   // [m*2 + ns], m = 0..3, ns = 0..1
#pragma unroll
    for (int x = 0; x < 8; ++x) acc[x] = (f32x16){};

    // identity k-order: layer l, n-group g: wtf + ((l*8+g)*16+kk)*512
    const _Float16* bp0 =
        wtf + ((size_t)(layer * 8 + 2 * wv) * 16) * 512 + lane * 8;
    const _Float16* bp1 = bp0 + 16 * 512;

#pragma unroll
    for (int kk = 0; kk < 16; ++kk) {
      f16x8 b0 = *(const f16x8*)(bp0 + (size_t)kk * 512);
      f16x8 b1 = *(const f16x8*)(bp1 + (size_t)kk * 512);
#pragma unroll
      for (int m = 0; m < 4; ++m) {
        f16x8 a = *(const f16x8*)(arow + (size_t)m * 32 * PADK + kk * 16);
        acc[m * 2]     = MFMA32(a, b0, acc[m * 2]);
        acc[m * 2 + 1] = MFMA32(a, b1, acc[m * 2 + 1]);
      }
    }

    if (layer < 3) {
      __syncthreads();   // all waves done reading As
      // C/D layout: col = lane&31, row = (reg&3) + 8*(reg>>2) + 4*h.
      // Identity act layout: contiguous 64B runs -> conflict-free.
#pragma unroll
      for (int m = 0; m < 4; ++m)
#pragma unroll
        for (int g = 0; g < 4; ++g)
#pragma unroll
          for (int r = 0; r < 4; ++r) {
            const int row = m * 32 + g * 8 + h * 4 + r;
            const int reg = g * 4 + r;
            As[row][n0 + c31]      = (_Float16)fmaxf(acc[m * 2][reg] + bv0, 0.f);
            As[row][n0 + 32 + c31] = (_Float16)fmaxf(acc[m * 2 + 1][reg] + bv1, 0.f);
          }
      __syncthreads();
    } else {
      // layer 4: bias + relu + pool over all 128 rows (this lane's h-half
      // of every m-tile = 64 rows); shfl_xor(32) folds the h-halves.
      float s0 = 0.f, s1 = 0.f;
#pragma unroll
      for (int m = 0; m < 4; ++m)
#pragma unroll
        for (int reg = 0; reg < 16; ++reg) {
          s0 += fmaxf(acc[m * 2][reg] + bv0, 0.f);
          s1 += fmaxf(acc[m * 2 + 1][reg] + bv1, 0.f);
        }
      s0 += __shfl_xor(s0, 32, 64);
      s1 += __shfl_xor(s1, 32, 64);
      if (h == 0) {
        atomicAdd(&xg[b * 256 + n0 + c31], s0);
        atomicAdd(&xg[b * 256 + n0 + 32 + c31], s1);
      }
    }
  }
}

// ---------------------------------------------------------------------------
// Kernel 2: f-MLP. One block per batch, 1024 threads: n = t&255 owns column,
// kc = t>>8 owns a 64-wide k-chunk; LDS reduce the 4 partials per column.
// ---------------------------------------------------------------------------
__global__ __launch_bounds__(1024) void f_mlp(
    const float* __restrict__ xg,
    const float* __restrict__ f1w, const float* __restrict__ f1b,
    const float* __restrict__ f2w, const float* __restrict__ f2b,
    const float* __restrict__ f3w, const float* __restrict__ f3b,
    float* __restrict__ out) {
  __shared__ float xs[256], ys[256], ps[4][256];
  const int b = blockIdx.x;
  const int t = threadIdx.x;
  const int n = t & 255;
  const int kc = t >> 8;

  if (t < 256) xs[t] = xg[b * 256 + t];
  __syncthreads();

  float p = 0.f;
#pragma unroll 8
  for (int k0 = 0; k0 < 64; ++k0) {
    int k = kc * 64 + k0;
    p += xs[k] * f1w[k * 256 + n];
  }
  ps[kc][n] = p;
  __syncthreads();
  if (t < 256)
    ys[t] = fmaxf(f1b[t] + ps[0][t] + ps[1][t] + ps[2][t] + ps[3][t], 0.f);
  __syncthreads();

  p = 0.f;
#pragma unroll 8
  for (int k0 = 0; k0 < 64; ++k0) {
    int k = kc * 64 + k0;
    p += ys[k] * f2w[k * 256 + n];
  }
  ps[kc][n] = p;
  __syncthreads();
  if (t < 256)
    xs[t] = fmaxf(f2b[t] + ps[0][t] + ps[1][t] + ps[2][t] + ps[3][t], 0.f);
  __syncthreads();

  p = 0.f;
#pragma unroll 8
  for (int k0 = 0; k0 < 64; ++k0) {
    int k = kc * 64 + k0;
    p += xs[k] * f3w[k * 256 + n];
  }
  ps[kc][n] = p;
  __syncthreads();
  if (t < 256)
    out[b * 256 + t] = f3b[t] + ps[0][t] + ps[1][t] + ps[2][t] + ps[3][t];
}

// ---------------------------------------------------------------------------
extern "C" void kernel_launch(void* const* d_in, const int* in_sizes, int n_in,
                              void* d_out, int out_size, void* d_ws, size_t ws_size,
                              hipStream_t stream) {
  const float* x_aux = (const float*)d_in[0];
  const float* g1w = (const float*)d_in[1];
  const float* g1b = (const float*)d_in[2];
  const float* g2w = (const float*)d_in[3];
  const float* g2b = (const float*)d_in[4];
  const float* g3w = (const float*)d_in[5];
  const float* g3b = (const float*)d_in[6];
  const float* g4w = (const float*)d_in[7];
  const float* g4b = (const float*)d_in[8];
  const float* f1w = (const float*)d_in[9];
  const float* f1b = (const float*)d_in[10];
  const float* f2w = (const float*)d_in[11];
  const float* f2b = (const float*)d_in[12];
  const float* f3w = (const float*)d_in[13];
  const float* f3b = (const float*)d_in[14];
  float* out = (float*)d_out;

  _Float16* wtf = (_Float16*)d_ws;                                  // 512 KB
  float* xg  = (float*)((char*)d_ws + 512u * 1024u);                // 32 KB
  float* cib = (float*)((char*)d_ws + 544u * 1024u);                // 2 MB
  float* h0j = (float*)((char*)d_ws + 544u * 1024u + 2048u * 1024u);// 2 MB

  hipLaunchKernelGGL(prep_all, dim3(800), dim3(256), 0, stream,
                     x_aux, g1w, g1b, g2w, g3w, g4w, wtf, xg, cib, h0j);
  hipLaunchKernelGGL(g_mlp_pool, dim3(BATCH * 32), dim3(256), 0, stream,
                     h0j, cib, wtf, g2b, g3b, g4b, xg);
  hipLaunchKernelGGL(f_mlp, dim3(BATCH), dim3(1024), 0, stream,
                     xg, f1w, f1b, f2w, f2b, f3w, f3b, out);
}